// Round 3
// baseline (818.602 us; speedup 1.0000x reference)
//
#include <hip/hip_runtime.h>
#include <cstddef>

// Problem constants (fixed by the reference).
#define B_ 256
#define S_ 10000
#define T_ 2000   // (10000 - 5)/5 + 1
#define TB_ 500   // T_/4
#define LOG2E 1.44269504088896340736f

// ---------- fast math helpers ----------
__device__ __forceinline__ float sigf(float x) {
  return __builtin_amdgcn_rcpf(1.f + __expf(-x));
}
__device__ __forceinline__ float rdlane(float v, int lane) {
  return __int_as_float(__builtin_amdgcn_readlane(__float_as_int(v), lane));
}

// DPP move (old=0). ctrl/row_mask must be ICE -> macro.
#define DPP_MOV(v, ctrl, rm, bc) \
  __int_as_float(__builtin_amdgcn_update_dpp(0, __float_as_int(v), (ctrl), (rm), 0xf, (bc)))

// Sum of all 64 lanes (distinct values). HW-verified R1/R2 (absmax 0.0).
__device__ __forceinline__ float wsum64(float v) {
  v += DPP_MOV(v, 0x111, 0xf, true);   // row_shr:1
  v += DPP_MOV(v, 0x112, 0xf, true);   // row_shr:2
  v += DPP_MOV(v, 0x114, 0xf, true);   // row_shr:4
  v += DPP_MOV(v, 0x118, 0xf, true);   // row_shr:8
  v += DPP_MOV(v, 0x142, 0xa, false);  // row_bcast15 -> rows 1,3
  v += DPP_MOV(v, 0x143, 0xc, false);  // row_bcast31 -> rows 2,3 ; lane63 = total
  return rdlane(v, 63);
}
// Sum of 16 distinct values for quad-replicated layout (lane j holds val[j>>2]),
// or any layout whose lanes {3,7,11,...,63} carry the values to be summed.
// HW-verified R1/R2 as wsum16q.
__device__ __forceinline__ float rsum16(float v) {
  v += DPP_MOV(v, 0x114, 0xf, true);   // row_shr:4
  v += DPP_MOV(v, 0x118, 0xf, true);   // row_shr:8
  v += DPP_MOV(v, 0x142, 0xa, false);  // row_bcast15
  v += DPP_MOV(v, 0x143, 0xc, false);  // row_bcast31
  return rdlane(v, 63);
}

// ---------- K0: precompute centered/scaled weights + covariance forms ----------
// Thread p (one wave) = gate index p. Outputs (all in d_ws):
//   W2h[p][m] = (Wh[p,m] - mean_rows(Wh)[m]) * (-sc_p*log2e*gh[p])
//   Ch [m][n] = (W~h^T W~h)[m,n] / 64        (W~ = row-centered Wh)
//   W2x, Cx   = same for Wx/gx
//   basex[p]  = -sc_p*log2e*(bx[p] + bG[p] + bh[p])
// where sc_p = 2 for g-gates (p in [32,48)) else 1 (folds tanh(g)=2*sig(2g)-1).
__global__ __launch_bounds__(64) void k_prep(
    const float* __restrict__ Wx, const float* __restrict__ Wh,
    const float* __restrict__ bG, const float* __restrict__ gx,
    const float* __restrict__ bx, const float* __restrict__ gh,
    const float* __restrict__ bh,
    float* __restrict__ W2h, float* __restrict__ Ch,
    float* __restrict__ W2x, float* __restrict__ Cx,
    float* __restrict__ basex) {
  __shared__ float ldsA[64][16];
  const int p = threadIdx.x;
  const float scl = ((p >> 4) == 2) ? (2.f * LOG2E) : LOG2E;
  const int m_ = p >> 2;
  const int n0 = (p & 3) * 4;

  // ---- H side ----
  {
    float wt[16];
#pragma unroll
    for (int m = 0; m < 16; ++m) {
      const float w = Wh[p * 16 + m];
      wt[m] = w - wsum64(w) * (1.f / 64.f);
    }
    const float ghl = -scl * gh[p];
#pragma unroll
    for (int m = 0; m < 16; ++m) {
      W2h[p * 16 + m] = wt[m] * ghl;
      ldsA[p][m] = wt[m];
    }
    __syncthreads();
    float a0 = 0.f, a1 = 0.f, a2 = 0.f, a3 = 0.f;
    for (int g = 0; g < 64; ++g) {
      const float a = ldsA[g][m_];
      a0 = fmaf(a, ldsA[g][n0 + 0], a0);
      a1 = fmaf(a, ldsA[g][n0 + 1], a1);
      a2 = fmaf(a, ldsA[g][n0 + 2], a2);
      a3 = fmaf(a, ldsA[g][n0 + 3], a3);
    }
    Ch[m_ * 16 + n0 + 0] = a0 * (1.f / 64.f);
    Ch[m_ * 16 + n0 + 1] = a1 * (1.f / 64.f);
    Ch[m_ * 16 + n0 + 2] = a2 * (1.f / 64.f);
    Ch[m_ * 16 + n0 + 3] = a3 * (1.f / 64.f);
    __syncthreads();
  }
  // ---- X side ----
  {
    float wt[16];
#pragma unroll
    for (int m = 0; m < 16; ++m) {
      const float w = Wx[p * 16 + m];
      wt[m] = w - wsum64(w) * (1.f / 64.f);
    }
    const float gxl = -scl * gx[p];
#pragma unroll
    for (int m = 0; m < 16; ++m) {
      W2x[p * 16 + m] = wt[m] * gxl;
      ldsA[p][m] = wt[m];
    }
    __syncthreads();
    float a0 = 0.f, a1 = 0.f, a2 = 0.f, a3 = 0.f;
    for (int g = 0; g < 64; ++g) {
      const float a = ldsA[g][m_];
      a0 = fmaf(a, ldsA[g][n0 + 0], a0);
      a1 = fmaf(a, ldsA[g][n0 + 1], a1);
      a2 = fmaf(a, ldsA[g][n0 + 2], a2);
      a3 = fmaf(a, ldsA[g][n0 + 3], a3);
    }
    Cx[m_ * 16 + n0 + 0] = a0 * (1.f / 64.f);
    Cx[m_ * 16 + n0 + 1] = a1 * (1.f / 64.f);
    Cx[m_ * 16 + n0 + 2] = a2 * (1.f / 64.f);
    Cx[m_ * 16 + n0 + 3] = a3 * (1.f / 64.f);
  }
  basex[p] = -scl * (bx[p] + bG[p] + bh[p]);
}

// ---------- K1: MLP(1->16)+ReLU -> Conv1d(16->16,k5,s5) -> sigmoid -> seq[B,T,16] ----------
__global__ __launch_bounds__(256) void k_conv(
    const float* __restrict__ x, const float* __restrict__ Wm,
    const float* __restrict__ bm, const float* __restrict__ Wc,
    const float* __restrict__ bconv, float* __restrict__ seq) {
  const int idx = blockIdx.x * 256 + threadIdx.x;
  const int b = idx / T_;
  const int t = idx - b * T_;
  const float* xp = x + (size_t)b * S_ + (size_t)t * 5;
  const float x0 = xp[0], x1 = xp[1], x2 = xp[2], x3 = xp[3], x4 = xp[4];
  float acc[16];
#pragma unroll
  for (int o = 0; o < 16; ++o) acc[o] = bconv[o];
#pragma unroll
  for (int i = 0; i < 16; ++i) {
    const float wmi = Wm[i], bmi = bm[i];
    const float u0 = fmaxf(fmaf(x0, wmi, bmi), 0.f);
    const float u1 = fmaxf(fmaf(x1, wmi, bmi), 0.f);
    const float u2 = fmaxf(fmaf(x2, wmi, bmi), 0.f);
    const float u3 = fmaxf(fmaf(x3, wmi, bmi), 0.f);
    const float u4 = fmaxf(fmaf(x4, wmi, bmi), 0.f);
#pragma unroll
    for (int o = 0; o < 16; ++o) {
      const float* w = Wc + o * 80 + i * 5;
      float a = acc[o];
      a = fmaf(u0, w[0], a);
      a = fmaf(u1, w[1], a);
      a = fmaf(u2, w[2], a);
      a = fmaf(u3, w[3], a);
      a = fmaf(u4, w[4], a);
      acc[o] = a;
    }
  }
  float4* sp = reinterpret_cast<float4*>(seq + (size_t)idx * 16);
#pragma unroll
  for (int qq = 0; qq < 4; ++qq) {
    float4 r;
    r.x = sigf(acc[qq * 4 + 0]);
    r.y = sigf(acc[qq * 4 + 1]);
    r.z = sigf(acc[qq * 4 + 2]);
    r.w = sigf(acc[qq * 4 + 3]);
    sp[qq] = r;
  }
}

// ---------- K2: packed x-gate precompute (centered-weight form) ----------
// One wave per (b,tb) = 4 timesteps. Lane j owns gate gj=(j&3)*16+(j>>2).
// sx = z2x * rsqrt(s'Cx s + eps) + basex, z2x = W2x[gj]·s  (all scales folded).
__global__ __launch_bounds__(256) void k_xgate(
    const float* __restrict__ seq, const float* __restrict__ W2x,
    const float* __restrict__ Cx, const float* __restrict__ basex,
    float4* __restrict__ xln4) {
  const int gtid = blockIdx.x * 256 + threadIdx.x;
  const int wid = __builtin_amdgcn_readfirstlane(gtid >> 6);  // b*TB_ + tb
  const int j = gtid & 63;
  const int k = j >> 2;
  const int gj = ((j & 3) << 4) | k;
  float w2[16], cr[16];
#pragma unroll
  for (int m = 0; m < 16; ++m) w2[m] = W2x[gj * 16 + m];
#pragma unroll
  for (int m = 0; m < 16; ++m) cr[m] = Cx[k * 16 + m];
  const float bse = basex[gj];
  const float epsj = (j == 3) ? 1e-5f : 0.f;
  const float* sv = seq + (size_t)wid * 64;  // wave-uniform -> s_loads
  float outv[4];
#pragma unroll
  for (int u = 0; u < 4; ++u) {
    const float* s0 = sv + u * 16;
    float z0 = w2[0] * s0[0], z1 = w2[4] * s0[4], z2_ = w2[8] * s0[8], z3 = w2[12] * s0[12];
    float v0 = cr[0] * s0[0], v1 = cr[4] * s0[4], v2_ = cr[8] * s0[8], v3 = cr[12] * s0[12];
#pragma unroll
    for (int m = 1; m < 4; ++m) {
      z0 = fmaf(w2[m], s0[m], z0);       v0 = fmaf(cr[m], s0[m], v0);
      z1 = fmaf(w2[4 + m], s0[4 + m], z1);   v1 = fmaf(cr[4 + m], s0[4 + m], v1);
      z2_ = fmaf(w2[8 + m], s0[8 + m], z2_); v2_ = fmaf(cr[8 + m], s0[8 + m], v2_);
      z3 = fmaf(w2[12 + m], s0[12 + m], z3); v3 = fmaf(cr[12 + m], s0[12 + m], v3);
    }
    const float z2 = (z0 + z1) + (z2_ + z3);
    const float v = (v0 + v1) + (v2_ + v3);
    const float sk = seq[(size_t)wid * 64 + u * 16 + k];  // per-lane load
    const float wq = fmaf(v, sk, epsj);
    const float S = rsum16(wq);           // = s'Cx s + eps (16 distinct, quad-same)
    const float rs = __builtin_amdgcn_rsqf(S);
    outv[u] = fmaf(z2, rs, bse);
  }
  float4 r;
  r.x = outv[0]; r.y = outv[1]; r.z = outv[2]; r.w = outv[3];
  xln4[(size_t)wid * 64 + j] = r;
}

// ---------- one LSTM step (centered-weight / covariance form) ----------
__device__ __forceinline__ float lstm_step2(
    float sx, float& c, const float hs[16], const float w2[16],
    const float cr[16], float hv, float epsj, float gcl, float bcl) {
  // z2 = W2h[gj]·h and v = Ch[k]·h -- both uniform-indexed (hs in SGPRs)
  float z0 = w2[0] * hs[0], z1 = w2[4] * hs[4], z2_ = w2[8] * hs[8], z3 = w2[12] * hs[12];
  float v0 = cr[0] * hs[0], v1 = cr[4] * hs[4], v2_ = cr[8] * hs[8], v3 = cr[12] * hs[12];
#pragma unroll
  for (int m = 1; m < 4; ++m) {
    z0 = fmaf(w2[m], hs[m], z0);         v0 = fmaf(cr[m], hs[m], v0);
    z1 = fmaf(w2[4 + m], hs[4 + m], z1); v1 = fmaf(cr[4 + m], hs[4 + m], v1);
    z2_ = fmaf(w2[8 + m], hs[8 + m], z2_); v2_ = fmaf(cr[8 + m], hs[8 + m], v2_);
    z3 = fmaf(w2[12 + m], hs[12 + m], z3); v3 = fmaf(cr[12 + m], hs[12 + m], v3);
  }
  const float z2 = (z0 + z1) + (z2_ + z3);
  const float v = (v0 + v1) + (v2_ + v3);
  const float wq = fmaf(v, hv, epsj);     // lane's k-term of h'Ch h (+eps at lane 3)
  const float S = rsum16(wq);             // var + eps (exact: W~ centers the mean)
  const float rs = __builtin_amdgcn_rsqf(S);
  const float arg = fmaf(z2, rs, sx);     // = -sc*log2e*gate
  const float e = exp2f(arg);
  const float r = __builtin_amdgcn_rcpf(1.f + e);  // sigma(sc*gate)
  // gather i,f,g,o within the quad (g still in sigma(2g) form)
  const float ivr = DPP_MOV(r, 0x00, 0xf, true);
  const float fvr = DPP_MOV(r, 0x55, 0xf, true);
  const float gvr = DPP_MOV(r, 0xAA, 0xf, true);
  const float ovr = DPP_MOV(r, 0xFF, 0xf, true);
  const float cf = fvr * c;
  const float gv2 = fmaf(2.f, gvr, -1.f); // tanh(g)
  c = fmaf(ivr, gv2, cf);
  const float t2 = c * gcl;               // gcl = 2*log2e*gc[k]
  const float c2 = c * c;
  const float csum = rsum16(c);
  const float c2sum = rsum16(c2);
  const float cm = csum * (1.f / 16.f);
  const float cmg = cm * gcl;
  const float nce = fmaf(cm, -cm, 1e-5f); // eps - cm^2
  const float cvv = fmaf(c2sum, 1.f / 16.f, nce);
  const float crs = __builtin_amdgcn_rsqf(cvv);
  const float Bc = fmaf(-cmg, crs, bcl);  // bcl = 2*log2e*bc[k]
  const float cn2 = fmaf(t2, crs, Bc);    // = 2*log2e*(LN(c)*gc+bc)
  const float e2 = exp2f(cn2);
  const float r2 = __builtin_amdgcn_rcpf(1.f + e2);
  const float ov2 = -2.f * ovr;
  return fmaf(ov2, r2, ovr);              // h = o * tanh(LN(c))
}

// ---------- K3: sequential LSTM scan, one wave per batch element ----------
__global__ __launch_bounds__(64) void k_lstm(
    const float4* __restrict__ xln4, const float* __restrict__ W2h,
    const float* __restrict__ Ch, const float* __restrict__ gc,
    const float* __restrict__ bc, const float* __restrict__ Wcls,
    const float* __restrict__ bcls, const float* __restrict__ h0,
    const float* __restrict__ c0, float* __restrict__ out) {
  const int b = blockIdx.x;
  const int j = threadIdx.x;
  const int k = j >> 2;
  const int gj = ((j & 3) << 4) | k;

  float w2[16], cr[16];
#pragma unroll
  for (int m = 0; m < 16; ++m) w2[m] = W2h[gj * 16 + m];
#pragma unroll
  for (int m = 0; m < 16; ++m) cr[m] = Ch[k * 16 + m];
  const float epsj = (j == 3) ? 1e-5f : 0.f;
  const float gcl = 2.f * LOG2E * gc[k];
  const float bcl = 2.f * LOG2E * bc[k];

  float c = c0[b * 16 + k];
  float hv = h0[b * 16 + k];   // per-lane copy of h[k] (quad-replicated)
  float hs[16];                // wave-uniform copy (SGPRs after readlane)
#pragma unroll
  for (int m = 0; m < 16; ++m) hs[m] = h0[b * 16 + m];

  const float4* xp = xln4 + (size_t)b * TB_ * 64 + j;
  float4 xc = xp[0];
  float4 xn = xp[64];
#pragma unroll 2
  for (int tb = 0; tb < TB_; ++tb) {
    const int tpf = (tb + 2 < TB_) ? (tb + 2) : (TB_ - 1);
    const float4 xf = xp[(size_t)tpf * 64];  // 8-step-ahead prefetch
    {
      hv = lstm_step2(xc.x, c, hs, w2, cr, hv, epsj, gcl, bcl);
#pragma unroll
      for (int m = 0; m < 16; ++m) hs[m] = rdlane(hv, 4 * m);
    }
    {
      hv = lstm_step2(xc.y, c, hs, w2, cr, hv, epsj, gcl, bcl);
#pragma unroll
      for (int m = 0; m < 16; ++m) hs[m] = rdlane(hv, 4 * m);
    }
    {
      hv = lstm_step2(xc.z, c, hs, w2, cr, hv, epsj, gcl, bcl);
#pragma unroll
      for (int m = 0; m < 16; ++m) hs[m] = rdlane(hv, 4 * m);
    }
    {
      hv = lstm_step2(xc.w, c, hs, w2, cr, hv, epsj, gcl, bcl);
#pragma unroll
      for (int m = 0; m < 16; ++m) hs[m] = rdlane(hv, 4 * m);
    }
    xc = xn;
    xn = xf;
  }

  float dot = bcls[0];
#pragma unroll
  for (int m = 0; m < 16; ++m) dot = fmaf(hs[m], Wcls[m], dot);
  if (j == 0) out[b] = sigf(dot);
}

// ---------- fallback (R2-proven path, used only if ws too small) ----------
__device__ __forceinline__ float lstm_step_ref(
    float sx, float& c, const float hs[16], const float wh[16],
    float ghp, float bhn, float amul, float abias, float gck2, float bck2) {
  float p0 = wh[0] * hs[0], p1 = wh[4] * hs[4], p2 = wh[8] * hs[8], p3 = wh[12] * hs[12];
#pragma unroll
  for (int m = 1; m < 4; ++m) {
    p0 = fmaf(wh[m], hs[m], p0);
    p1 = fmaf(wh[4 + m], hs[4 + m], p1);
    p2 = fmaf(wh[8 + m], hs[8 + m], p2);
    p3 = fmaf(wh[12 + m], hs[12 + m], p3);
  }
  const float z = (p0 + p1) + (p2 + p3);
  const float s = wsum64(z);
  const float s2 = wsum64(z * z);
  const float mean = s * (1.f / 64.f);
  const float var = fmaf(s2, (1.f / 64.f), -mean * mean);
  const float rs = __builtin_amdgcn_rsqf(var + 1e-5f);
  const float P = rs * ghp;
  const float tB = sx + bhn;
  const float Bv = fmaf(mean, P, tB);
  const float ngate = fmaf(-z, P, Bv);
  const float r = __builtin_amdgcn_rcpf(1.f + __expf(ngate));
  const float act = fmaf(amul, r, abias);
  const float iv = DPP_MOV(act, 0x00, 0xf, true);
  const float fv = DPP_MOV(act, 0x55, 0xf, true);
  const float gv = DPP_MOV(act, 0xAA, 0xf, true);
  const float ov = DPP_MOV(act, 0xFF, 0xf, true);
  c = fmaf(fv, c, iv * gv);
  const float ov2 = -2.f * ov;
  const float cs = rsum16(c);
  const float cs2 = rsum16(c * c);
  const float cm = cs * (1.f / 16.f);
  const float cvv = fmaf(cs2, (1.f / 16.f), -cm * cm);
  const float crs = __builtin_amdgcn_rsqf(cvv + 1e-5f);
  const float Ac = crs * gck2;
  const float Bc = fmaf(-cm, Ac, bck2);
  const float cn2 = fmaf(c, Ac, Bc);
  const float r2 = __builtin_amdgcn_rcpf(1.f + __expf(cn2));
  return fmaf(ov2, r2, ov);
}

__global__ __launch_bounds__(64) void k_lstm_fb(
    const float* __restrict__ seq, const float* __restrict__ Wx,
    const float* __restrict__ Wh, const float* __restrict__ bG,
    const float* __restrict__ gx, const float* __restrict__ bx,
    const float* __restrict__ gh, const float* __restrict__ bh,
    const float* __restrict__ gc, const float* __restrict__ bc,
    const float* __restrict__ Wcls, const float* __restrict__ bcls,
    const float* __restrict__ h0, const float* __restrict__ c0,
    float* __restrict__ out) {
  const int b = blockIdx.x;
  const int j = threadIdx.x;
  const int q = j & 3;
  const int k = j >> 2;
  const int gj = (q << 4) | k;
  float wh[16], wx[16];
#pragma unroll
  for (int m = 0; m < 16; ++m) wh[m] = Wh[gj * 16 + m];
#pragma unroll
  for (int m = 0; m < 16; ++m) wx[m] = Wx[gj * 16 + m];
  const float sc = (q == 2) ? 2.f : 1.f;
  const float ghp = gh[gj] * sc;
  const float bhn = -bh[gj] * sc;
  const float amul = (q == 2) ? 2.f : 1.f;
  const float abias = (q == 2) ? -1.f : 0.f;
  const float gck2 = 2.f * gc[k];
  const float bck2 = 2.f * bc[k];
  const float gxa = gx[gj] * -sc;
  const float bxa = (bx[gj] + bG[gj]) * -sc;
  float c = c0[b * 16 + k];
  float hs[16];
#pragma unroll
  for (int m = 0; m < 16; ++m) hs[m] = h0[b * 16 + m];
  const float* sv0 = seq + (size_t)b * T_ * 16;
  for (int t = 0; t < T_; ++t) {
    const float* sv = sv0 + (size_t)t * 16;
    float za = 0.f, zb = 0.f;
#pragma unroll
    for (int m = 0; m < 8; ++m) za = fmaf(sv[m], wx[m], za);
#pragma unroll
    for (int m = 8; m < 16; ++m) zb = fmaf(sv[m], wx[m], zb);
    const float z = za + zb;
    const float s = wsum64(z);
    const float s2 = wsum64(z * z);
    const float mean = s * (1.f / 64.f);
    const float var = fmaf(s2, 1.f / 64.f, -mean * mean);
    const float rs = __builtin_amdgcn_rsqf(var + 1e-5f);
    const float sx = fmaf((z - mean) * rs, gxa, bxa);
    const float hvv = lstm_step_ref(sx, c, hs, wh, ghp, bhn, amul, abias, gck2, bck2);
#pragma unroll
    for (int m = 0; m < 16; ++m) hs[m] = rdlane(hvv, 4 * m);
  }
  float dot = bcls[0];
#pragma unroll
  for (int m = 0; m < 16; ++m) dot = fmaf(hs[m], Wcls[m], dot);
  if (j == 0) out[b] = sigf(dot);
}

// ---------- host ----------
extern "C" void kernel_launch(void* const* d_in, const int* in_sizes, int n_in,
                              void* d_out, int out_size, void* d_ws, size_t ws_size,
                              hipStream_t stream) {
  (void)in_sizes; (void)n_in; (void)out_size;
  const float* x    = (const float*)d_in[0];
  const float* Wm   = (const float*)d_in[1];
  const float* bm   = (const float*)d_in[2];
  const float* Wc   = (const float*)d_in[3];
  const float* bcv  = (const float*)d_in[4];
  const float* Wx   = (const float*)d_in[5];
  const float* Wh   = (const float*)d_in[6];
  const float* bG   = (const float*)d_in[7];
  const float* gx   = (const float*)d_in[8];
  const float* bx   = (const float*)d_in[9];
  const float* gh   = (const float*)d_in[10];
  const float* bh   = (const float*)d_in[11];
  const float* gc   = (const float*)d_in[12];
  const float* bc   = (const float*)d_in[13];
  const float* Wcls = (const float*)d_in[14];
  const float* bcls = (const float*)d_in[15];
  const float* h0   = (const float*)d_in[16];
  const float* c0   = (const float*)d_in[17];
  float* out = (float*)d_out;

  const size_t seq_bytes = (size_t)B_ * T_ * 16 * sizeof(float);     // 32.768 MB
  const size_t xln_bytes = (size_t)B_ * TB_ * 64 * sizeof(float4);   // 131.072 MB
  const size_t prep_bytes = (1024 + 256 + 1024 + 256 + 64) * sizeof(float);
  float* seq = (float*)d_ws;
  float4* xln4 = (float4*)((char*)d_ws + seq_bytes);
  float* prep = (float*)((char*)d_ws + seq_bytes + xln_bytes);
  float* W2h = prep;
  float* Ch = W2h + 1024;
  float* W2x = Ch + 256;
  float* Cx = W2x + 1024;
  float* basex = Cx + 256;
  const bool use_xln = ws_size >= seq_bytes + xln_bytes + prep_bytes;

  k_conv<<<dim3((B_ * T_) / 256), dim3(256), 0, stream>>>(x, Wm, bm, Wc, bcv, seq);
  if (use_xln) {
    k_prep<<<dim3(1), dim3(64), 0, stream>>>(Wx, Wh, bG, gx, bx, gh, bh,
                                             W2h, Ch, W2x, Cx, basex);
    k_xgate<<<dim3((B_ * TB_ * 64) / 256), dim3(256), 0, stream>>>(
        seq, W2x, Cx, basex, xln4);
    k_lstm<<<dim3(B_), dim3(64), 0, stream>>>(
        xln4, W2h, Ch, gc, bc, Wcls, bcls, h0, c0, out);
  } else {
    k_lstm_fb<<<dim3(B_), dim3(64), 0, stream>>>(
        seq, Wx, Wh, bG, gx, bx, gh, bh, gc, bc, Wcls, bcls, h0, c0, out);
  }
}

// Round 4
// 676.499 us; speedup vs baseline: 1.2101x; 1.2101x over previous
//
#include <hip/hip_runtime.h>
#include <cstddef>

// Problem constants (fixed by the reference).
#define B_ 256
#define S_ 10000
#define T_ 2000   // (10000 - 5)/5 + 1
#define TB_ 500   // T_/4
#define LOG2E 1.44269504088896340736f

typedef float v2f __attribute__((ext_vector_type(2)));

// ---------- fast math helpers ----------
__device__ __forceinline__ float sigf(float x) {
  return __builtin_amdgcn_rcpf(1.f + __expf(-x));
}
__device__ __forceinline__ float rdlane(float v, int lane) {
  return __int_as_float(__builtin_amdgcn_readlane(__float_as_int(v), lane));
}
__device__ __forceinline__ v2f pkfma(v2f a, v2f b, v2f c) {
#if __has_builtin(__builtin_elementwise_fma)
  return __builtin_elementwise_fma(a, b, c);
#else
  return a * b + c;   // -ffp-contract=fast fuses
#endif
}

// DPP move (old=0). ctrl/row_mask must be ICE -> macro.
#define DPP_MOV(v, ctrl, rm, bc) \
  __int_as_float(__builtin_amdgcn_update_dpp(0, __float_as_int(v), (ctrl), (rm), 0xf, (bc)))

// Sum of all 64 lanes (distinct values). HW-verified R1-R3 (absmax 0.0).
__device__ __forceinline__ float wsum64(float v) {
  v += DPP_MOV(v, 0x111, 0xf, true);   // row_shr:1
  v += DPP_MOV(v, 0x112, 0xf, true);   // row_shr:2
  v += DPP_MOV(v, 0x114, 0xf, true);   // row_shr:4
  v += DPP_MOV(v, 0x118, 0xf, true);   // row_shr:8
  v += DPP_MOV(v, 0x142, 0xa, false);  // row_bcast15 -> rows 1,3
  v += DPP_MOV(v, 0x143, 0xc, false);  // row_bcast31 -> rows 2,3 ; lane63 = total
  return rdlane(v, 63);
}
// Sum of 16 distinct values carried on lanes {3,7,...,63} (quad-replicated data).
// HW-verified R1-R3.
__device__ __forceinline__ float rsum16(float v) {
  v += DPP_MOV(v, 0x114, 0xf, true);   // row_shr:4
  v += DPP_MOV(v, 0x118, 0xf, true);   // row_shr:8
  v += DPP_MOV(v, 0x142, 0xa, false);  // row_bcast15
  v += DPP_MOV(v, 0x143, 0xc, false);  // row_bcast31
  return rdlane(v, 63);
}

// ---------- K0: precompute centered/scaled weights + covariance forms ----------
// (unchanged from R3 -- HW-verified)
__global__ __launch_bounds__(64) void k_prep(
    const float* __restrict__ Wx, const float* __restrict__ Wh,
    const float* __restrict__ bG, const float* __restrict__ gx,
    const float* __restrict__ bx, const float* __restrict__ gh,
    const float* __restrict__ bh,
    float* __restrict__ W2h, float* __restrict__ Ch,
    float* __restrict__ W2x, float* __restrict__ Cx,
    float* __restrict__ basex) {
  __shared__ float ldsA[64][16];
  const int p = threadIdx.x;
  const float scl = ((p >> 4) == 2) ? (2.f * LOG2E) : LOG2E;
  const int m_ = p >> 2;
  const int n0 = (p & 3) * 4;
  // ---- H side ----
  {
    float wt[16];
#pragma unroll
    for (int m = 0; m < 16; ++m) {
      const float w = Wh[p * 16 + m];
      wt[m] = w - wsum64(w) * (1.f / 64.f);
    }
    const float ghl = -scl * gh[p];
#pragma unroll
    for (int m = 0; m < 16; ++m) {
      W2h[p * 16 + m] = wt[m] * ghl;
      ldsA[p][m] = wt[m];
    }
    __syncthreads();
    float a0 = 0.f, a1 = 0.f, a2 = 0.f, a3 = 0.f;
    for (int g = 0; g < 64; ++g) {
      const float a = ldsA[g][m_];
      a0 = fmaf(a, ldsA[g][n0 + 0], a0);
      a1 = fmaf(a, ldsA[g][n0 + 1], a1);
      a2 = fmaf(a, ldsA[g][n0 + 2], a2);
      a3 = fmaf(a, ldsA[g][n0 + 3], a3);
    }
    Ch[m_ * 16 + n0 + 0] = a0 * (1.f / 64.f);
    Ch[m_ * 16 + n0 + 1] = a1 * (1.f / 64.f);
    Ch[m_ * 16 + n0 + 2] = a2 * (1.f / 64.f);
    Ch[m_ * 16 + n0 + 3] = a3 * (1.f / 64.f);
    __syncthreads();
  }
  // ---- X side ----
  {
    float wt[16];
#pragma unroll
    for (int m = 0; m < 16; ++m) {
      const float w = Wx[p * 16 + m];
      wt[m] = w - wsum64(w) * (1.f / 64.f);
    }
    const float gxl = -scl * gx[p];
#pragma unroll
    for (int m = 0; m < 16; ++m) {
      W2x[p * 16 + m] = wt[m] * gxl;
      ldsA[p][m] = wt[m];
    }
    __syncthreads();
    float a0 = 0.f, a1 = 0.f, a2 = 0.f, a3 = 0.f;
    for (int g = 0; g < 64; ++g) {
      const float a = ldsA[g][m_];
      a0 = fmaf(a, ldsA[g][n0 + 0], a0);
      a1 = fmaf(a, ldsA[g][n0 + 1], a1);
      a2 = fmaf(a, ldsA[g][n0 + 2], a2);
      a3 = fmaf(a, ldsA[g][n0 + 3], a3);
    }
    Cx[m_ * 16 + n0 + 0] = a0 * (1.f / 64.f);
    Cx[m_ * 16 + n0 + 1] = a1 * (1.f / 64.f);
    Cx[m_ * 16 + n0 + 2] = a2 * (1.f / 64.f);
    Cx[m_ * 16 + n0 + 3] = a3 * (1.f / 64.f);
  }
  basex[p] = -scl * (bx[p] + bG[p] + bh[p]);
}

// ---------- K1: MLP(1->16)+ReLU -> Conv1d(16->16,k5,s5) -> sigmoid -> seq[B,T,16] ----------
__global__ __launch_bounds__(256) void k_conv(
    const float* __restrict__ x, const float* __restrict__ Wm,
    const float* __restrict__ bm, const float* __restrict__ Wc,
    const float* __restrict__ bconv, float* __restrict__ seq) {
  const int idx = blockIdx.x * 256 + threadIdx.x;
  const int b = idx / T_;
  const int t = idx - b * T_;
  const float* xp = x + (size_t)b * S_ + (size_t)t * 5;
  const float x0 = xp[0], x1 = xp[1], x2 = xp[2], x3 = xp[3], x4 = xp[4];
  float acc[16];
#pragma unroll
  for (int o = 0; o < 16; ++o) acc[o] = bconv[o];
#pragma unroll
  for (int i = 0; i < 16; ++i) {
    const float wmi = Wm[i], bmi = bm[i];
    const float u0 = fmaxf(fmaf(x0, wmi, bmi), 0.f);
    const float u1 = fmaxf(fmaf(x1, wmi, bmi), 0.f);
    const float u2 = fmaxf(fmaf(x2, wmi, bmi), 0.f);
    const float u3 = fmaxf(fmaf(x3, wmi, bmi), 0.f);
    const float u4 = fmaxf(fmaf(x4, wmi, bmi), 0.f);
#pragma unroll
    for (int o = 0; o < 16; ++o) {
      const float* w = Wc + o * 80 + i * 5;
      float a = acc[o];
      a = fmaf(u0, w[0], a);
      a = fmaf(u1, w[1], a);
      a = fmaf(u2, w[2], a);
      a = fmaf(u3, w[3], a);
      a = fmaf(u4, w[4], a);
      acc[o] = a;
    }
  }
  float4* sp = reinterpret_cast<float4*>(seq + (size_t)idx * 16);
#pragma unroll
  for (int qq = 0; qq < 4; ++qq) {
    float4 r;
    r.x = sigf(acc[qq * 4 + 0]);
    r.y = sigf(acc[qq * 4 + 1]);
    r.z = sigf(acc[qq * 4 + 2]);
    r.w = sigf(acc[qq * 4 + 3]);
    sp[qq] = r;
  }
}

// ---------- K2: packed x-gate precompute (centered-weight form, R3-verified) ----------
__global__ __launch_bounds__(256) void k_xgate(
    const float* __restrict__ seq, const float* __restrict__ W2x,
    const float* __restrict__ Cx, const float* __restrict__ basex,
    float4* __restrict__ xln4) {
  const int gtid = blockIdx.x * 256 + threadIdx.x;
  const int wid = __builtin_amdgcn_readfirstlane(gtid >> 6);  // b*TB_ + tb
  const int j = gtid & 63;
  const int k = j >> 2;
  const int gj = ((j & 3) << 4) | k;
  float w2[16], cr[16];
#pragma unroll
  for (int m = 0; m < 16; ++m) w2[m] = W2x[gj * 16 + m];
#pragma unroll
  for (int m = 0; m < 16; ++m) cr[m] = Cx[k * 16 + m];
  const float bse = basex[gj];
  const float epsj = (j == 3) ? 1e-5f : 0.f;
  const float* sv = seq + (size_t)wid * 64;
  float outv[4];
#pragma unroll
  for (int u = 0; u < 4; ++u) {
    const float* s0 = sv + u * 16;
    float z0 = w2[0] * s0[0], z1 = w2[4] * s0[4], z2_ = w2[8] * s0[8], z3 = w2[12] * s0[12];
    float v0 = cr[0] * s0[0], v1 = cr[4] * s0[4], v2_ = cr[8] * s0[8], v3 = cr[12] * s0[12];
#pragma unroll
    for (int m = 1; m < 4; ++m) {
      z0 = fmaf(w2[m], s0[m], z0);       v0 = fmaf(cr[m], s0[m], v0);
      z1 = fmaf(w2[4 + m], s0[4 + m], z1);   v1 = fmaf(cr[4 + m], s0[4 + m], v1);
      z2_ = fmaf(w2[8 + m], s0[8 + m], z2_); v2_ = fmaf(cr[8 + m], s0[8 + m], v2_);
      z3 = fmaf(w2[12 + m], s0[12 + m], z3); v3 = fmaf(cr[12 + m], s0[12 + m], v3);
    }
    const float z2 = (z0 + z1) + (z2_ + z3);
    const float v = (v0 + v1) + (v2_ + v3);
    const float sk = seq[(size_t)wid * 64 + u * 16 + k];
    const float wq = fmaf(v, sk, epsj);
    const float S = rsum16(wq);
    const float rs = __builtin_amdgcn_rsqf(S);
    outv[u] = fmaf(z2, rs, bse);
  }
  float4 r;
  r.x = outv[0]; r.y = outv[1]; r.z = outv[2]; r.w = outv[3];
  xln4[(size_t)wid * 64 + j] = r;
}

// ---------- one LSTM step: LDS h-broadcast + packed-f32 matvec ----------
// hsh4: 4 float4 in LDS holding h[0..15]; wz/wv: packed (pairs over m) rows.
// Returns new hv (lane j holds h[j>>2], quad-replicated) and stores it to LDS.
__device__ __forceinline__ float lstm_step4(
    float sx, float& c, const float4* hsh4, float* hshw, int k,
    const v2f wz[8], const v2f wv[8], float hv, float epsj,
    float gcl, float bcl) {
  const float4 A = hsh4[0], Bq = hsh4[1], Cq = hsh4[2], Dq = hsh4[3];
  const v2f h0_ = {A.x, A.y},  h1_ = {A.z, A.w};
  const v2f h2_ = {Bq.x, Bq.y}, h3_ = {Bq.z, Bq.w};
  const v2f h4_ = {Cq.x, Cq.y}, h5_ = {Cq.z, Cq.w};
  const v2f h6_ = {Dq.x, Dq.y}, h7_ = {Dq.z, Dq.w};
  // z-stream (W2h row) and v-stream (Ch row), 4 indep chains of 2 each
  v2f za = pkfma(wz[1], h1_, wz[0] * h0_);
  v2f zb = pkfma(wz[3], h3_, wz[2] * h2_);
  v2f zc = pkfma(wz[5], h5_, wz[4] * h4_);
  v2f zd = pkfma(wz[7], h7_, wz[6] * h6_);
  v2f va = pkfma(wv[1], h1_, wv[0] * h0_);
  v2f vb = pkfma(wv[3], h3_, wv[2] * h2_);
  v2f vc = pkfma(wv[5], h5_, wv[4] * h4_);
  v2f vd = pkfma(wv[7], h7_, wv[6] * h6_);
  const v2f zs = (za + zb) + (zc + zd);
  const v2f vs = (va + vb) + (vc + vd);
  const float z2 = zs.x + zs.y;           // = W2h[gj] . h
  const float v = vs.x + vs.y;            // = Ch[k] . h
  const float wq = fmaf(v, hv, epsj);     // lane's k-term of h'Ch h (+eps lane 3)
  const float S = rsum16(wq);             // var + eps (centered weights)
  const float rs = __builtin_amdgcn_rsqf(S);
  const float arg = fmaf(z2, rs, sx);     // = -sc*log2e*gate
  const float e = exp2f(arg);
  const float r = __builtin_amdgcn_rcpf(1.f + e);  // sigma(sc*gate)
  const float ivr = DPP_MOV(r, 0x00, 0xf, true);
  const float fvr = DPP_MOV(r, 0x55, 0xf, true);
  const float gvr = DPP_MOV(r, 0xAA, 0xf, true);
  const float ovr = DPP_MOV(r, 0xFF, 0xf, true);
  const float cf = fvr * c;
  const float gv2 = fmaf(2.f, gvr, -1.f); // tanh(g)
  c = fmaf(ivr, gv2, cf);
  const float t2 = c * gcl;               // gcl = 2*log2e*gc[k]
  const float c2 = c * c;
  const float csum = rsum16(c);
  const float c2sum = rsum16(c2);
  const float cm = csum * (1.f / 16.f);
  const float cmg = cm * gcl;
  const float nce = fmaf(cm, -cm, 1e-5f);
  const float cvv = fmaf(c2sum, 1.f / 16.f, nce);
  const float crs = __builtin_amdgcn_rsqf(cvv);
  const float Bc = fmaf(-cmg, crs, bcl);  // bcl = 2*log2e*bc[k]
  const float cn2 = fmaf(t2, crs, Bc);
  const float e2 = exp2f(cn2);
  const float r2 = __builtin_amdgcn_rcpf(1.f + e2);
  const float ov2 = -2.f * ovr;
  const float hnew = fmaf(ov2, r2, ovr);  // h = o*tanh(LN(c))
  hshw[k] = hnew;                         // ds_write_b32 (quad same-value write)
  return hnew;
}

// ---------- K3: sequential LSTM scan, one wave per batch element ----------
__global__ __launch_bounds__(64) void k_lstm(
    const float4* __restrict__ xln4, const float* __restrict__ W2h,
    const float* __restrict__ Ch, const float* __restrict__ gc,
    const float* __restrict__ bc, const float* __restrict__ Wcls,
    const float* __restrict__ bcls, const float* __restrict__ h0,
    const float* __restrict__ c0, float* __restrict__ out) {
  __shared__ float4 hsh4[4];
  float* hshw = (float*)hsh4;
  const int b = blockIdx.x;
  const int j = threadIdx.x;
  const int k = j >> 2;
  const int gj = ((j & 3) << 4) | k;

  v2f wz[8], wv[8];
#pragma unroll
  for (int m = 0; m < 8; ++m) {
    wz[m] = v2f{W2h[gj * 16 + 2 * m], W2h[gj * 16 + 2 * m + 1]};
    wv[m] = v2f{Ch[k * 16 + 2 * m], Ch[k * 16 + 2 * m + 1]};
  }
  const float epsj = (j == 3) ? 1e-5f : 0.f;
  const float gcl = 2.f * LOG2E * gc[k];
  const float bcl = 2.f * LOG2E * bc[k];

  float c = c0[b * 16 + k];
  float hv = h0[b * 16 + k];   // per-lane h[k] (quad-replicated)
  hshw[k] = hv;                // seed LDS with h0 (all quads write same value)

  const float4* xp = xln4 + (size_t)b * TB_ * 64 + j;
  float4 xc = xp[0];
  float4 xn = xp[64];
#pragma unroll 2
  for (int tb = 0; tb < TB_; ++tb) {
    const int tpf = (tb + 2 < TB_) ? (tb + 2) : (TB_ - 1);
    const float4 xf = xp[(size_t)tpf * 64];  // 8-step-ahead prefetch
    hv = lstm_step4(xc.x, c, hsh4, hshw, k, wz, wv, hv, epsj, gcl, bcl);
    hv = lstm_step4(xc.y, c, hsh4, hshw, k, wz, wv, hv, epsj, gcl, bcl);
    hv = lstm_step4(xc.z, c, hsh4, hshw, k, wz, wv, hv, epsj, gcl, bcl);
    hv = lstm_step4(xc.w, c, hsh4, hshw, k, wz, wv, hv, epsj, gcl, bcl);
    xc = xn;
    xn = xf;
  }

  if (j == 0) {
    float dot = bcls[0];
#pragma unroll
    for (int m = 0; m < 16; ++m) dot = fmaf(hshw[m], Wcls[m], dot);
    out[b] = sigf(dot);
  }
}

// ---------- fallback (R2-proven path, used only if ws too small) ----------
__device__ __forceinline__ float lstm_step_ref(
    float sx, float& c, const float hs[16], const float wh[16],
    float ghp, float bhn, float amul, float abias, float gck2, float bck2) {
  float p0 = wh[0] * hs[0], p1 = wh[4] * hs[4], p2 = wh[8] * hs[8], p3 = wh[12] * hs[12];
#pragma unroll
  for (int m = 1; m < 4; ++m) {
    p0 = fmaf(wh[m], hs[m], p0);
    p1 = fmaf(wh[4 + m], hs[4 + m], p1);
    p2 = fmaf(wh[8 + m], hs[8 + m], p2);
    p3 = fmaf(wh[12 + m], hs[12 + m], p3);
  }
  const float z = (p0 + p1) + (p2 + p3);
  const float s = wsum64(z);
  const float s2 = wsum64(z * z);
  const float mean = s * (1.f / 64.f);
  const float var = fmaf(s2, (1.f / 64.f), -mean * mean);
  const float rs = __builtin_amdgcn_rsqf(var + 1e-5f);
  const float P = rs * ghp;
  const float tB = sx + bhn;
  const float Bv = fmaf(mean, P, tB);
  const float ngate = fmaf(-z, P, Bv);
  const float r = __builtin_amdgcn_rcpf(1.f + __expf(ngate));
  const float act = fmaf(amul, r, abias);
  const float iv = DPP_MOV(act, 0x00, 0xf, true);
  const float fv = DPP_MOV(act, 0x55, 0xf, true);
  const float gv = DPP_MOV(act, 0xAA, 0xf, true);
  const float ov = DPP_MOV(act, 0xFF, 0xf, true);
  c = fmaf(fv, c, iv * gv);
  const float ov2 = -2.f * ov;
  const float cs = rsum16(c);
  const float cs2 = rsum16(c * c);
  const float cm = cs * (1.f / 16.f);
  const float cvv = fmaf(cs2, (1.f / 16.f), -cm * cm);
  const float crs = __builtin_amdgcn_rsqf(cvv + 1e-5f);
  const float Ac = crs * gck2;
  const float Bc = fmaf(-cm, Ac, bck2);
  const float cn2 = fmaf(c, Ac, Bc);
  const float r2 = __builtin_amdgcn_rcpf(1.f + __expf(cn2));
  return fmaf(ov2, r2, ov);
}

__global__ __launch_bounds__(64) void k_lstm_fb(
    const float* __restrict__ seq, const float* __restrict__ Wx,
    const float* __restrict__ Wh, const float* __restrict__ bG,
    const float* __restrict__ gx, const float* __restrict__ bx,
    const float* __restrict__ gh, const float* __restrict__ bh,
    const float* __restrict__ gc, const float* __restrict__ bc,
    const float* __restrict__ Wcls, const float* __restrict__ bcls,
    const float* __restrict__ h0, const float* __restrict__ c0,
    float* __restrict__ out) {
  const int b = blockIdx.x;
  const int j = threadIdx.x;
  const int q = j & 3;
  const int k = j >> 2;
  const int gj = (q << 4) | k;
  float wh[16], wx[16];
#pragma unroll
  for (int m = 0; m < 16; ++m) wh[m] = Wh[gj * 16 + m];
#pragma unroll
  for (int m = 0; m < 16; ++m) wx[m] = Wx[gj * 16 + m];
  const float sc = (q == 2) ? 2.f : 1.f;
  const float ghp = gh[gj] * sc;
  const float bhn = -bh[gj] * sc;
  const float amul = (q == 2) ? 2.f : 1.f;
  const float abias = (q == 2) ? -1.f : 0.f;
  const float gck2 = 2.f * gc[k];
  const float bck2 = 2.f * bc[k];
  const float gxa = gx[gj] * -sc;
  const float bxa = (bx[gj] + bG[gj]) * -sc;
  float c = c0[b * 16 + k];
  float hs[16];
#pragma unroll
  for (int m = 0; m < 16; ++m) hs[m] = h0[b * 16 + m];
  const float* sv0 = seq + (size_t)b * T_ * 16;
  for (int t = 0; t < T_; ++t) {
    const float* sv = sv0 + (size_t)t * 16;
    float za = 0.f, zb = 0.f;
#pragma unroll
    for (int m = 0; m < 8; ++m) za = fmaf(sv[m], wx[m], za);
#pragma unroll
    for (int m = 8; m < 16; ++m) zb = fmaf(sv[m], wx[m], zb);
    const float z = za + zb;
    const float s = wsum64(z);
    const float s2 = wsum64(z * z);
    const float mean = s * (1.f / 64.f);
    const float var = fmaf(s2, 1.f / 64.f, -mean * mean);
    const float rs = __builtin_amdgcn_rsqf(var + 1e-5f);
    const float sx = fmaf((z - mean) * rs, gxa, bxa);
    const float hvv = lstm_step_ref(sx, c, hs, wh, ghp, bhn, amul, abias, gck2, bck2);
#pragma unroll
    for (int m = 0; m < 16; ++m) hs[m] = rdlane(hvv, 4 * m);
  }
  float dot = bcls[0];
#pragma unroll
  for (int m = 0; m < 16; ++m) dot = fmaf(hs[m], Wcls[m], dot);
  if (j == 0) out[b] = sigf(dot);
}

// ---------- host ----------
extern "C" void kernel_launch(void* const* d_in, const int* in_sizes, int n_in,
                              void* d_out, int out_size, void* d_ws, size_t ws_size,
                              hipStream_t stream) {
  (void)in_sizes; (void)n_in; (void)out_size;
  const float* x    = (const float*)d_in[0];
  const float* Wm   = (const float*)d_in[1];
  const float* bm   = (const float*)d_in[2];
  const float* Wc   = (const float*)d_in[3];
  const float* bcv  = (const float*)d_in[4];
  const float* Wx   = (const float*)d_in[5];
  const float* Wh   = (const float*)d_in[6];
  const float* bG   = (const float*)d_in[7];
  const float* gx   = (const float*)d_in[8];
  const float* bx   = (const float*)d_in[9];
  const float* gh   = (const float*)d_in[10];
  const float* bh   = (const float*)d_in[11];
  const float* gc   = (const float*)d_in[12];
  const float* bc   = (const float*)d_in[13];
  const float* Wcls = (const float*)d_in[14];
  const float* bcls = (const float*)d_in[15];
  const float* h0   = (const float*)d_in[16];
  const float* c0   = (const float*)d_in[17];
  float* out = (float*)d_out;

  const size_t seq_bytes = (size_t)B_ * T_ * 16 * sizeof(float);     // 32.768 MB
  const size_t xln_bytes = (size_t)B_ * TB_ * 64 * sizeof(float4);   // 131.072 MB
  const size_t prep_bytes = (1024 + 256 + 1024 + 256 + 64) * sizeof(float);
  float* seq = (float*)d_ws;
  float4* xln4 = (float4*)((char*)d_ws + seq_bytes);
  float* prep = (float*)((char*)d_ws + seq_bytes + xln_bytes);
  float* W2h = prep;
  float* Ch = W2h + 1024;
  float* W2x = Ch + 256;
  float* Cx = W2x + 1024;
  float* basex = Cx + 256;
  const bool use_xln = ws_size >= seq_bytes + xln_bytes + prep_bytes;

  if (use_xln) {
    k_prep<<<dim3(1), dim3(64), 0, stream>>>(Wx, Wh, bG, gx, bx, gh, bh,
                                             W2h, Ch, W2x, Cx, basex);
    k_conv<<<dim3((B_ * T_) / 256), dim3(256), 0, stream>>>(x, Wm, bm, Wc, bcv, seq);
    k_xgate<<<dim3((B_ * TB_ * 64) / 256), dim3(256), 0, stream>>>(
        seq, W2x, Cx, basex, xln4);
    k_lstm<<<dim3(B_), dim3(64), 0, stream>>>(
        xln4, W2h, Ch, gc, bc, Wcls, bcls, h0, c0, out);
  } else {
    k_conv<<<dim3((B_ * T_) / 256), dim3(256), 0, stream>>>(x, Wm, bm, Wc, bcv, seq);
    k_lstm_fb<<<dim3(B_), dim3(64), 0, stream>>>(
        seq, Wx, Wh, bG, gx, bx, gh, bh, gc, bc, Wcls, bcls, h0, c0, out);
  }
}